// Round 3
// baseline (416.761 us; speedup 1.0000x reference)
//
#include <hip/hip_runtime.h>
#include <hip/hip_bf16.h>

// NodeModel fused GNN block, round 3.
// Key change vs round 2: edge_attr is permuted into sorted-by-destination
// order with STREAMING reads + scattered writes (scatter_fast), so the hot
// edge kernel reads bf16 rows fully streaming. Mean folded into h1-GEMM.
//   y    = x @ W1a[0:128] + b1a                  (bf16, 40k x 128)
//   t_e  = EAS[p] @ W1a[128:192]                 (MFMA, raw acc -> LDS)
//   sums = segmented-sum over sorted p of relu(y[row_p] + t_p)
//   h1   = relu(x@W2c + (sums/cnt)@(W1b@W2a_mid) + b2a + [cnt>0]*bc + (u@W2a_u)[batch])
//   out  = h1 @ W2b + b2b

typedef __bf16 bf16x8 __attribute__((ext_vector_type(8)));
typedef float f32x4v __attribute__((ext_vector_type(4)));

#define NN 40000
#define NE 640000

__device__ inline bf16x8 cvt8(const float* __restrict__ p) {
  f32x4v a = *(const f32x4v*)p;
  f32x4v b = *(const f32x4v*)(p + 4);
  bf16x8 r;
  r[0] = (__bf16)a[0]; r[1] = (__bf16)a[1]; r[2] = (__bf16)a[2]; r[3] = (__bf16)a[3];
  r[4] = (__bf16)b[0]; r[5] = (__bf16)b[1]; r[6] = (__bf16)b[2]; r[7] = (__bf16)b[3];
  return r;
}
__device__ inline bf16x8 cvt8s(const float* __restrict__ p, float s) {
  f32x4v a = *(const f32x4v*)p;
  f32x4v b = *(const f32x4v*)(p + 4);
  bf16x8 r;
  r[0] = (__bf16)(a[0]*s); r[1] = (__bf16)(a[1]*s); r[2] = (__bf16)(a[2]*s); r[3] = (__bf16)(a[3]*s);
  r[4] = (__bf16)(b[0]*s); r[5] = (__bf16)(b[1]*s); r[6] = (__bf16)(b[2]*s); r[7] = (__bf16)(b[3]*s);
  return r;
}

// ---------------- prep: bf16 B^T weight tables + small folds ----------------
__global__ __launch_bounds__(256) void prep(
    const float* __restrict__ W1a, const float* __restrict__ W2a,
    const float* __restrict__ W2b, const float* __restrict__ W1b,
    const float* __restrict__ b1b, const float* __restrict__ u,
    __bf16* __restrict__ WTya,   // 128x128 (W1a rows 0..127 ^T)
    __bf16* __restrict__ WTeb,   // 128x64  (W1a rows 128..191 ^T)
    __bf16* __restrict__ WT2c,   // 128x128 (W2a rows 0..127 ^T)
    __bf16* __restrict__ WT2bT,  // 128x128
    __bf16* __restrict__ WT2d,   // 128x128 ((W1b @ W2a[128:256])^T)
    float* __restrict__ vtab,    // 64x128  (u @ W2a[256:320])
    float* __restrict__ bc)      // 128     (b1b @ W2a[128:256])
{
  int b = blockIdx.x, t = threadIdx.x;
  if (b < 64) {
    int idx = b * 256 + t; int n = idx & 127; int k = idx >> 7;
    WTya[n * 128 + k] = (__bf16)W1a[k * 128 + n];
  } else if (b < 96) {
    int idx = (b - 64) * 256 + t; int n = idx & 127; int k = idx >> 7;   // k 0..63
    WTeb[n * 64 + k] = (__bf16)W1a[(128 + k) * 128 + n];
  } else if (b < 160) {
    int idx = (b - 96) * 256 + t; int n = idx & 127; int k = idx >> 7;
    WT2c[n * 128 + k] = (__bf16)W2a[k * 128 + n];
  } else if (b < 224) {
    int idx = (b - 160) * 256 + t; int n = idx & 127; int k = idx >> 7;
    WT2bT[n * 128 + k] = (__bf16)W2b[k * 128 + n];
  } else if (b < 256) {
    int idx = (b - 224) * 256 + t; int n = idx & 127; int gi = idx >> 7;
    float s = 0.f;
    for (int k = 0; k < 64; ++k) s += u[gi * 64 + k] * W2a[(256 + k) * 128 + n];
    vtab[gi * 128 + n] = s;
  } else if (b == 256) {
    if (t < 128) {
      float s = 0.f;
      for (int j = 0; j < 128; ++j) s += b1b[j] * W2a[(128 + j) * 128 + t];
      bc[t] = s;
    }
  } else {
    int k = b - 257;
    if (t < 128) {
      float s = 0.f;
      for (int j = 0; j < 128; ++j) s += W1b[k * 128 + j] * W2a[(128 + j) * 128 + t];
      WT2d[t * 128 + k] = (__bf16)s;
    }
  }
}

// ---------------- counting sort -------------------------------------------
__global__ __launch_bounds__(256) void hist_kernel(const int* __restrict__ EI,
                                                   int* __restrict__ cnt) {
  int e = blockIdx.x * 256 + threadIdx.x;
  atomicAdd(&cnt[EI[NE + e]], 1);
}

__global__ __launch_bounds__(1024) void scan_kernel(const int* __restrict__ cnt,
                                                    int* __restrict__ offsets) {
  __shared__ int part[1024];
  int t = threadIdx.x;
  int base = t * 40;
  int s = 0;
  for (int k = 0; k < 40; ++k) { int idx = base + k; if (idx < NN) s += cnt[idx]; }
  part[t] = s;
  __syncthreads();
  for (int off = 1; off < 1024; off <<= 1) {
    int v = (t >= off) ? part[t - off] : 0;
    __syncthreads();
    part[t] += v;
    __syncthreads();
  }
  int pre = part[t] - s;
  for (int k = 0; k < 40; ++k) {
    int idx = base + k;
    if (idx < NN) { offsets[idx] = pre; pre += cnt[idx]; }
  }
}

// FAST: streaming-read EA, convert bf16, scattered-write into sorted slots.
// 8 threads per edge; block = 32 edges; 20000 blocks.
__global__ __launch_bounds__(256) void scatter_fast(
    const int* __restrict__ EI, const float* __restrict__ EA,
    int* __restrict__ offs, unsigned* __restrict__ srcid,
    __bf16* __restrict__ EAS) {
  int t = threadIdx.x;
  int e = blockIdx.x * 32 + (t >> 3);
  int part = t & 7;
  int lane = t & 63;
  int pos = 0;
  if (part == 0) {
    int col = EI[NE + e];
    pos = atomicAdd(&offs[col], 1);
    int row = EI[e];
    srcid[2 * (size_t)pos] = ((unsigned)row << 16) | (unsigned)col;
  }
  pos = __shfl(pos, lane & ~7, 64);
  bf16x8 v = cvt8(EA + (size_t)e * 64 + part * 8);
  *(bf16x8*)(EAS + (size_t)pos * 64 + part * 8) = v;
}

// FALLBACK: ids only (edge kernel gathers EA f32 itself).
__global__ __launch_bounds__(256) void scatter_fb(const int* __restrict__ EI,
                                                  int* __restrict__ offs,
                                                  unsigned* __restrict__ srcid) {
  int e = blockIdx.x * 256 + threadIdx.x;
  int col = EI[NE + e];
  int row = EI[e];
  int pos = atomicAdd(&offs[col], 1);
  srcid[2 * (size_t)pos]     = ((unsigned)row << 16) | (unsigned)col;
  srcid[2 * (size_t)pos + 1] = (unsigned)e;
}

// ---------------- fused edge GEMM + segmented scatter-reduce ----------------
__global__ __launch_bounds__(256) void edge_fast(
    const __bf16* __restrict__ EAS,      // sorted, 640000x64 bf16
    const unsigned* __restrict__ srcid,  // [2*i] = row<<16|col
    const __bf16* __restrict__ WTeb,     // 128x64
    const __bf16* __restrict__ Yb,       // 40000x128 bf16
    float* __restrict__ SUMS)            // 40000x128 f32, zeroed
{
  __shared__ float vbuf[64 * 132];
  __shared__ int lrow[64], lcol[64];
  int t = threadIdx.x;
  int i0 = blockIdx.x * 64;
  if (t < 64) {
    unsigned rc = srcid[2 * (size_t)(i0 + t)];
    lrow[t] = (int)(rc >> 16);
    lcol[t] = (int)(rc & 0xffffu);
  }
  __syncthreads();

  int lane = t & 63, w = t >> 6, g = lane >> 4, c = lane & 15;
  f32x4v acc[8];
#pragma unroll
  for (int nt = 0; nt < 8; ++nt) acc[nt] = (f32x4v)(0.f);

  const __bf16* arow = EAS + (size_t)(i0 + w * 16 + c) * 64;
#pragma unroll
  for (int kk = 0; kk < 64; kk += 32) {
    bf16x8 af = *(const bf16x8*)(arow + kk + g * 8);
#pragma unroll
    for (int nt = 0; nt < 8; ++nt) {
      bf16x8 bf = *(const bf16x8*)(WTeb + (nt * 16 + c) * 64 + kk + g * 8);
      acc[nt] = __builtin_amdgcn_mfma_f32_16x16x32_bf16(af, bf, acc[nt], 0, 0, 0);
    }
  }
#pragma unroll
  for (int q = 0; q < 4; ++q) {
    int r = w * 16 + g * 4 + q;
#pragma unroll
    for (int nt = 0; nt < 8; ++nt)
      vbuf[r * 132 + nt * 16 + c] = acc[nt][q];
  }
  __syncthreads();

  int h = t >> 7, n = t & 127;
  int rbase = h * 32;
  float sum = 0.f;
  int cur = lcol[rbase];
#pragma unroll 8
  for (int r = rbase; r < rbase + 32; ++r) {
    int col = lcol[r];
    float yv = (float)Yb[(size_t)lrow[r] * 128 + n];
    float v = fmaxf(vbuf[r * 132 + n] + yv, 0.f);
    if (col != cur) {
      unsafeAtomicAdd(&SUMS[(size_t)cur * 128 + n], sum);
      sum = 0.f; cur = col;
    }
    sum += v;
  }
  unsafeAtomicAdd(&SUMS[(size_t)cur * 128 + n], sum);
}

__global__ __launch_bounds__(256) void edge_fb(
    const float* __restrict__ EA,
    const unsigned* __restrict__ srcid,  // [2i]=rowcol, [2i+1]=edge id
    const __bf16* __restrict__ WTeb,
    const __bf16* __restrict__ Yb,
    float* __restrict__ SUMS)
{
  __shared__ float vbuf[64 * 132];
  __shared__ int lrow[64], lcol[64], ledge[64];
  int t = threadIdx.x;
  int i0 = blockIdx.x * 64;
  if (t < 64) {
    unsigned rc = srcid[2 * (size_t)(i0 + t)];
    lrow[t] = (int)(rc >> 16);
    lcol[t] = (int)(rc & 0xffffu);
    ledge[t] = (int)srcid[2 * (size_t)(i0 + t) + 1];
  }
  __syncthreads();

  int lane = t & 63, w = t >> 6, g = lane >> 4, c = lane & 15;
  f32x4v acc[8];
#pragma unroll
  for (int nt = 0; nt < 8; ++nt) acc[nt] = (f32x4v)(0.f);

  const float* arow = EA + (size_t)ledge[w * 16 + c] * 64;
#pragma unroll
  for (int kk = 0; kk < 64; kk += 32) {
    bf16x8 af = cvt8(arow + kk + g * 8);
#pragma unroll
    for (int nt = 0; nt < 8; ++nt) {
      bf16x8 bf = *(const bf16x8*)(WTeb + (nt * 16 + c) * 64 + kk + g * 8);
      acc[nt] = __builtin_amdgcn_mfma_f32_16x16x32_bf16(af, bf, acc[nt], 0, 0, 0);
    }
  }
#pragma unroll
  for (int q = 0; q < 4; ++q) {
    int r = w * 16 + g * 4 + q;
#pragma unroll
    for (int nt = 0; nt < 8; ++nt)
      vbuf[r * 132 + nt * 16 + c] = acc[nt][q];
  }
  __syncthreads();

  int h = t >> 7, n = t & 127;
  int rbase = h * 32;
  float sum = 0.f;
  int cur = lcol[rbase];
#pragma unroll 8
  for (int r = rbase; r < rbase + 32; ++r) {
    int col = lcol[r];
    float yv = (float)Yb[(size_t)lrow[r] * 128 + n];
    float v = fmaxf(vbuf[r * 132 + n] + yv, 0.f);
    if (col != cur) {
      unsafeAtomicAdd(&SUMS[(size_t)cur * 128 + n], sum);
      sum = 0.f; cur = col;
    }
    sum += v;
  }
  unsafeAtomicAdd(&SUMS[(size_t)cur * 128 + n], sum);
}

// ---------------- node-level GEMM (N=128) ----------------------------------
// acc = A1 @ BT1 [+ (A2f * rowscale) @ BT2]; epilogue: +cbias, +[cnt>0]*gbias,
// +vtab[vidx[r]], optional relu; store f32 or bf16.
__global__ __launch_bounds__(256) void mlp_gemm(
    const float* __restrict__ A1f, const __bf16* __restrict__ A1b,
    int K1, int lda1, const __bf16* __restrict__ BT1, int ldb1,
    const float* __restrict__ A2f, int K2, int lda2,
    const __bf16* __restrict__ BT2, int ldb2,
    const int* __restrict__ cnt,
    const float* __restrict__ cbias, const float* __restrict__ gbias,
    const float* __restrict__ vtab, const int* __restrict__ vidx,
    int do_relu, float* __restrict__ Cf, __bf16* __restrict__ Cb) {
  int lane = threadIdx.x & 63;
  int wave = threadIdx.x >> 6;
  int rowbase = blockIdx.x * 64 + wave * 16;
  int g = lane >> 4, c = lane & 15;

  f32x4v acc[8];
#pragma unroll
  for (int nt = 0; nt < 8; ++nt) acc[nt] = (f32x4v)(0.f);

  if (A1f) {
    const float* arow = A1f + (size_t)(rowbase + c) * lda1;
    for (int kk = 0; kk < K1; kk += 32) {
      bf16x8 af = cvt8(arow + kk + g * 8);
#pragma unroll
      for (int nt = 0; nt < 8; ++nt) {
        bf16x8 bf = *(const bf16x8*)(BT1 + (size_t)(nt * 16 + c) * ldb1 + kk + g * 8);
        acc[nt] = __builtin_amdgcn_mfma_f32_16x16x32_bf16(af, bf, acc[nt], 0, 0, 0);
      }
    }
  } else {
    const __bf16* arow = A1b + (size_t)(rowbase + c) * lda1;
    for (int kk = 0; kk < K1; kk += 32) {
      bf16x8 af = *(const bf16x8*)(arow + kk + g * 8);
#pragma unroll
      for (int nt = 0; nt < 8; ++nt) {
        bf16x8 bf = *(const bf16x8*)(BT1 + (size_t)(nt * 16 + c) * ldb1 + kk + g * 8);
        acc[nt] = __builtin_amdgcn_mfma_f32_16x16x32_bf16(af, bf, acc[nt], 0, 0, 0);
      }
    }
  }
  if (A2f) {
    float inv = 1.f;
    if (cnt) inv = 1.f / fmaxf((float)cnt[rowbase + c], 1.f);
    const float* arow2 = A2f + (size_t)(rowbase + c) * lda2;
    for (int kk = 0; kk < K2; kk += 32) {
      bf16x8 af = cvt8s(arow2 + kk + g * 8, inv);
#pragma unroll
      for (int nt = 0; nt < 8; ++nt) {
        bf16x8 bf = *(const bf16x8*)(BT2 + (size_t)(nt * 16 + c) * ldb2 + kk + g * 8);
        acc[nt] = __builtin_amdgcn_mfma_f32_16x16x32_bf16(af, bf, acc[nt], 0, 0, 0);
      }
    }
  }

#pragma unroll
  for (int q = 0; q < 4; ++q) {
    int r = rowbase + g * 4 + q;
    float gmul = 0.f;
    if (gbias) gmul = cnt[r] ? 1.f : 0.f;
    const float* vrow = vtab ? (vtab + (size_t)vidx[r] * 128) : nullptr;
#pragma unroll
    for (int nt = 0; nt < 8; ++nt) {
      int n = nt * 16 + c;
      float v = acc[nt][q];
      if (cbias) v += cbias[n];
      if (gbias) v += gmul * gbias[n];
      if (vrow) v += vrow[n];
      if (do_relu) v = fmaxf(v, 0.f);
      if (Cb) Cb[(size_t)r * 128 + n] = (__bf16)v;
      else    Cf[(size_t)r * 128 + n] = v;
    }
  }
}

extern "C" void kernel_launch(void* const* d_in, const int* in_sizes, int n_in,
                              void* d_out, int out_size, void* d_ws, size_t ws_size,
                              hipStream_t stream) {
  const float* x    = (const float*)d_in[0];
  const int*   ei   = (const int*)d_in[1];
  const float* ea   = (const float*)d_in[2];
  const float* u    = (const float*)d_in[3];
  const int*   batch= (const int*)d_in[4];
  const float* W1a  = (const float*)d_in[5];
  const float* b1a  = (const float*)d_in[6];
  const float* W1b  = (const float*)d_in[7];
  const float* b1b  = (const float*)d_in[8];
  const float* W2a  = (const float*)d_in[9];
  const float* b2a  = (const float*)d_in[10];
  const float* W2b  = (const float*)d_in[11];
  const float* b2b  = (const float*)d_in[12];

  char* ws = (char*)d_ws;
  __bf16* WTya   = (__bf16*)(ws);                 // 32768
  __bf16* WTeb   = (__bf16*)(ws + 32768);         // 16384
  __bf16* WT2c   = (__bf16*)(ws + 49152);         // 32768
  __bf16* WT2bT  = (__bf16*)(ws + 81920);         // 32768
  __bf16* WT2d   = (__bf16*)(ws + 114688);        // 32768
  float*  vtab   = (float*)(ws + 147456);         // 32768
  float*  bc     = (float*)(ws + 180224);         // 512
  float*  sums   = (float*)(ws + 180736);         // 20,480,000
  int*    cnt    = (int*)(ws + 20660736);         // 160,000
  int*    offs   = (int*)(ws + 20820736);         // 160,000
  __bf16* ybufb  = (__bf16*)(ws + 20980736);      // 10,240,000 (Yb, then h1b)
  unsigned* srcid= (unsigned*)(ws + 31220736);    // 5,120,000 (rowcol,id pairs)
  __bf16* EAS    = (__bf16*)(ws + 36340736);      // 81,920,000 (fast path only)
  __bf16* h1b    = ybufb;                          // Yb dead after edge kernel

  const size_t FAST_NEED = 36340736ull + 81920000ull;  // 118,260,736
  int fast = (ws_size >= FAST_NEED) ? 1 : 0;

  // zero atomic accumulators (sums + cnt contiguous)
  hipMemsetAsync(ws + 180736, 0, 20480000 + 160000, stream);

  prep<<<385, 256, 0, stream>>>(W1a, W2a, W2b, W1b, b1b, u,
                                WTya, WTeb, WT2c, WT2bT, WT2d, vtab, bc);

  hist_kernel<<<2500, 256, 0, stream>>>(ei, cnt);
  scan_kernel<<<1, 1024, 0, stream>>>(cnt, offs);
  if (fast)
    scatter_fast<<<20000, 256, 0, stream>>>(ei, ea, offs, srcid, EAS);
  else
    scatter_fb<<<2500, 256, 0, stream>>>(ei, offs, srcid);

  // y = x @ W1a_top + b1a  -> bf16
  mlp_gemm<<<625, 256, 0, stream>>>(x, nullptr, 128, 128, WTya, 128,
                                    nullptr, 0, 0, nullptr, 0,
                                    nullptr, b1a, nullptr, nullptr, nullptr,
                                    0, nullptr, ybufb);

  if (fast)
    edge_fast<<<10000, 256, 0, stream>>>(EAS, srcid, WTeb, ybufb, sums);
  else
    edge_fb<<<10000, 256, 0, stream>>>(ea, srcid, WTeb, ybufb, sums);

  // h1 = relu(x@WT2c + (sums/cnt)@WT2d + b2a + [cnt>0]*bc + vtab[batch]) -> bf16
  mlp_gemm<<<625, 256, 0, stream>>>(x, nullptr, 128, 128, WT2c, 128,
                                    sums, 128, 128, WT2d, 128,
                                    cnt, b2a, bc, vtab, batch,
                                    1, nullptr, h1b);

  // out = h1 @ W2b + b2b  -> f32
  mlp_gemm<<<625, 256, 0, stream>>>(nullptr, h1b, 128, 128, WT2bT, 128,
                                    nullptr, 0, 0, nullptr, 0,
                                    nullptr, b2b, nullptr, nullptr, nullptr,
                                    0, (float*)d_out, nullptr);
}

// Round 4
// 410.850 us; speedup vs baseline: 1.0144x; 1.0144x over previous
//
#include <hip/hip_runtime.h>
#include <hip/hip_bf16.h>

// NodeModel fused GNN block, round 4: E/R split.
//   y     = x @ W1a[0:128] + b1a                          (bf16, 40k x 128)
//   TMP[e]= bf16(relu(y[row_e] + EA[e] @ W1a[128:192]))   (streaming E, no sort)
//   mean  = (sum of TMP rows per dest node via CSR) / max(cnt,1)   (R, no atomics)
//   h1    = relu(x@W2c + mean@(W1b@W2a_mid) + b2a + [cnt>0]*bc + (u@W2a_u)[batch])
//   out   = h1 @ W2b + b2b
// Edges chunked (2 x 320k) when ws_size < 188 MB so TMP fits in proven ws.

typedef __bf16 bf16x8 __attribute__((ext_vector_type(8)));
typedef float f32x4v __attribute__((ext_vector_type(4)));

#define NN 40000
#define NE 640000

__device__ inline bf16x8 cvt8(const float* __restrict__ p) {
  f32x4v a = *(const f32x4v*)p;
  f32x4v b = *(const f32x4v*)(p + 4);
  bf16x8 r;
  r[0] = (__bf16)a[0]; r[1] = (__bf16)a[1]; r[2] = (__bf16)a[2]; r[3] = (__bf16)a[3];
  r[4] = (__bf16)b[0]; r[5] = (__bf16)b[1]; r[6] = (__bf16)b[2]; r[7] = (__bf16)b[3];
  return r;
}

// ---------------- prep: bf16 B^T weight tables + small folds ----------------
__global__ __launch_bounds__(256) void prep(
    const float* __restrict__ W1a, const float* __restrict__ W2a,
    const float* __restrict__ W2b, const float* __restrict__ W1b,
    const float* __restrict__ b1b, const float* __restrict__ u,
    __bf16* __restrict__ WTya,   // 128x128 (W1a rows 0..127 ^T)
    __bf16* __restrict__ WTeb,   // 128x64  (W1a rows 128..191 ^T)
    __bf16* __restrict__ WT2c,   // 128x128 (W2a rows 0..127 ^T)
    __bf16* __restrict__ WT2bT,  // 128x128
    __bf16* __restrict__ WT2d,   // 128x128 ((W1b @ W2a[128:256])^T)
    float* __restrict__ vtab,    // 64x128  (u @ W2a[256:320])
    float* __restrict__ bc)      // 128     (b1b @ W2a[128:256])
{
  int b = blockIdx.x, t = threadIdx.x;
  if (b < 64) {
    int idx = b * 256 + t; int n = idx & 127; int k = idx >> 7;
    WTya[n * 128 + k] = (__bf16)W1a[k * 128 + n];
  } else if (b < 96) {
    int idx = (b - 64) * 256 + t; int n = idx & 127; int k = idx >> 7;   // k 0..63
    WTeb[n * 64 + k] = (__bf16)W1a[(128 + k) * 128 + n];
  } else if (b < 160) {
    int idx = (b - 96) * 256 + t; int n = idx & 127; int k = idx >> 7;
    WT2c[n * 128 + k] = (__bf16)W2a[k * 128 + n];
  } else if (b < 224) {
    int idx = (b - 160) * 256 + t; int n = idx & 127; int k = idx >> 7;
    WT2bT[n * 128 + k] = (__bf16)W2b[k * 128 + n];
  } else if (b < 256) {
    int idx = (b - 224) * 256 + t; int n = idx & 127; int gi = idx >> 7;
    float s = 0.f;
    for (int k = 0; k < 64; ++k) s += u[gi * 64 + k] * W2a[(256 + k) * 128 + n];
    vtab[gi * 128 + n] = s;
  } else if (b == 256) {
    if (t < 128) {
      float s = 0.f;
      for (int j = 0; j < 128; ++j) s += b1b[j] * W2a[(128 + j) * 128 + t];
      bc[t] = s;
    }
  } else {
    int k = b - 257;
    if (t < 128) {
      float s = 0.f;
      for (int j = 0; j < 128; ++j) s += W1b[k * 128 + j] * W2a[(128 + j) * 128 + t];
      WT2d[t * 128 + k] = (__bf16)s;
    }
  }
}

// ---------------- per-chunk counting-sort of edge IDS only ------------------
__global__ __launch_bounds__(256) void hist2(const int* __restrict__ EI,
                                             int* __restrict__ cnt0,
                                             int* __restrict__ cnt1, int ech) {
  int e = blockIdx.x * 256 + threadIdx.x;   // grid covers NE exactly
  int col = EI[NE + e];
  if (e < ech) atomicAdd(&cnt0[col], 1);
  else         atomicAdd(&cnt1[col], 1);
}

__global__ __launch_bounds__(1024) void scan2(const int* __restrict__ cnt0,
                                              int* __restrict__ offs0,
                                              const int* __restrict__ cnt1,
                                              int* __restrict__ offs1) {
  const int* cnt = blockIdx.x ? cnt1 : cnt0;
  int* offs      = blockIdx.x ? offs1 : offs0;
  __shared__ int part[1024];
  int t = threadIdx.x;
  int base = t * 40;
  int s = 0;
  for (int k = 0; k < 40; ++k) { int idx = base + k; if (idx < NN) s += cnt[idx]; }
  part[t] = s;
  __syncthreads();
  for (int off = 1; off < 1024; off <<= 1) {
    int v = (t >= off) ? part[t - off] : 0;
    __syncthreads();
    part[t] += v;
    __syncthreads();
  }
  int pre = part[t] - s;
  for (int k = 0; k < 40; ++k) {
    int idx = base + k;
    if (idx < NN) { offs[idx] = pre; pre += cnt[idx]; }
  }
}

__global__ __launch_bounds__(256) void scatter2(const int* __restrict__ EI,
                                                int* __restrict__ offs0,
                                                int* __restrict__ offs1,
                                                int* __restrict__ sedge0,
                                                int* __restrict__ sedge1, int ech) {
  int e = blockIdx.x * 256 + threadIdx.x;
  int col = EI[NE + e];
  if (e < ech) { int p = atomicAdd(&offs0[col], 1); sedge0[p] = e; }
  else         { int p = atomicAdd(&offs1[col], 1); sedge1[p] = e; }
}

__global__ __launch_bounds__(256) void totk(const int* __restrict__ c0,
                                            const int* __restrict__ c1,
                                            int* __restrict__ ct) {
  int i = blockIdx.x * 256 + threadIdx.x;
  if (i < NN) ct[i] = c0[i] + c1[i];
}

// ---------------- E: streaming edge GEMM + y-add + relu -> bf16 TMP ---------
// block = 256 thr = 4 waves x 16 edges = 64 edges; grid = chunk_edges/64.
__global__ __launch_bounds__(256) void edge_E(
    const float* __restrict__ EA,    // 640000x64 f32 (global)
    const int* __restrict__ EI,      // [2][640000]
    const __bf16* __restrict__ WTeb, // 128x64
    const __bf16* __restrict__ Yb,   // 40000x128 bf16
    __bf16* __restrict__ TMP,        // chunk_edges x 128 bf16 (chunk-local)
    int e0)                          // chunk base edge id
{
  __shared__ __bf16 vb16[64 * 136];
  __shared__ int lrow[64];
  int t = threadIdx.x;
  int i0l = blockIdx.x * 64;          // chunk-local base
  if (t < 64) lrow[t] = EI[e0 + i0l + t];
  __syncthreads();

  int lane = t & 63, w = t >> 6, g = lane >> 4, c = lane & 15;
  f32x4v acc[8];
#pragma unroll
  for (int nt = 0; nt < 8; ++nt) acc[nt] = (f32x4v)(0.f);

  const float* arow = EA + (size_t)(e0 + i0l + w * 16 + c) * 64;
#pragma unroll
  for (int kk = 0; kk < 64; kk += 32) {
    bf16x8 af = cvt8(arow + kk + g * 8);
#pragma unroll
    for (int nt = 0; nt < 8; ++nt) {
      bf16x8 bf = *(const bf16x8*)(WTeb + (nt * 16 + c) * 64 + kk + g * 8);
      acc[nt] = __builtin_amdgcn_mfma_f32_16x16x32_bf16(af, bf, acc[nt], 0, 0, 0);
    }
  }

  // batch-gather y values for this thread's acc elements (independent loads)
  float yv[4][8];
#pragma unroll
  for (int q = 0; q < 4; ++q) {
    int r = w * 16 + g * 4 + q;
    const __bf16* yr = Yb + (size_t)lrow[r] * 128;
#pragma unroll
    for (int nt = 0; nt < 8; ++nt) yv[q][nt] = (float)yr[nt * 16 + c];
  }
#pragma unroll
  for (int q = 0; q < 4; ++q) {
    int r = w * 16 + g * 4 + q;
#pragma unroll
    for (int nt = 0; nt < 8; ++nt) {
      float v = fmaxf(acc[nt][q] + yv[q][nt], 0.f);
      vb16[r * 136 + nt * 16 + c] = (__bf16)v;
    }
  }
  __syncthreads();

  // coalesced bf16x8 row stores: 64 rows x 16 chunks, 4 per thread
#pragma unroll
  for (int k2 = 0; k2 < 4; ++k2) {
    int ch = t + k2 * 256;
    int row = ch >> 4, c8 = ch & 15;
    bf16x8 vv = *(const bf16x8*)(vb16 + row * 136 + c8 * 8);
    *(bf16x8*)(TMP + ((size_t)(i0l + row)) * 128 + c8 * 8) = vv;
  }
}

// ---------------- R: node-centric CSR gather-reduce (no atomics) ------------
// wave per node, lane owns cols {2*lane, 2*lane+1}; block = 4 nodes.
__global__ __launch_bounds__(256) void node_R(
    const __bf16* __restrict__ TMP,    // chunk-local rows
    const int* __restrict__ sedgec,    // chunk's sorted edge ids
    const int* __restrict__ cntc,      // per-node in-chunk count
    const int* __restrict__ offsc,     // per-node END offset (post-scatter)
    const __bf16* __restrict__ partial,// partial sums from prev chunk (or null)
    const int* __restrict__ cntT,      // total counts (final only)
    int e0, int fin,
    __bf16* __restrict__ outb)         // partial sums or final mean
{
  int node = blockIdx.x * 4 + (threadIdx.x >> 6);  // grid*4 == NN exactly
  int lane = threadIdx.x & 63;
  int m = cntc[node];
  int start = offsc[node] - m;
  float s0 = 0.f, s1 = 0.f;
#pragma unroll 4
  for (int j = 0; j < m; ++j) {
    int e = sedgec[start + j];
    unsigned uu = *(const unsigned*)(TMP + ((size_t)(e - e0)) * 128 + lane * 2);
    s0 += __builtin_bit_cast(float, uu << 16);
    s1 += __builtin_bit_cast(float, uu & 0xffff0000u);
  }
  if (partial) {
    unsigned pu = *(const unsigned*)(partial + (size_t)node * 128 + lane * 2);
    s0 += __builtin_bit_cast(float, pu << 16);
    s1 += __builtin_bit_cast(float, pu & 0xffff0000u);
  }
  if (fin) {
    float inv = 1.f / fmaxf((float)cntT[node], 1.f);
    s0 *= inv; s1 *= inv;
  }
  unsigned r0 = (unsigned)__builtin_bit_cast(unsigned short, (__bf16)s0);
  unsigned r1 = (unsigned)__builtin_bit_cast(unsigned short, (__bf16)s1);
  *(unsigned*)(outb + (size_t)node * 128 + lane * 2) = r0 | (r1 << 16);
}

// ---------------- node-level GEMM (N=128) ----------------------------------
__global__ __launch_bounds__(256) void mlp_gemm(
    const float* __restrict__ A1f, const __bf16* __restrict__ A1b,
    int K1, int lda1, const __bf16* __restrict__ BT1, int ldb1,
    const __bf16* __restrict__ A2b, int K2, int lda2,
    const __bf16* __restrict__ BT2, int ldb2,
    const int* __restrict__ cnt,
    const float* __restrict__ cbias, const float* __restrict__ gbias,
    const float* __restrict__ vtab, const int* __restrict__ vidx,
    int do_relu, float* __restrict__ Cf, __bf16* __restrict__ Cb) {
  int lane = threadIdx.x & 63;
  int wave = threadIdx.x >> 6;
  int rowbase = blockIdx.x * 64 + wave * 16;
  int g = lane >> 4, c = lane & 15;

  f32x4v acc[8];
#pragma unroll
  for (int nt = 0; nt < 8; ++nt) acc[nt] = (f32x4v)(0.f);

  if (A1f) {
    const float* arow = A1f + (size_t)(rowbase + c) * lda1;
    for (int kk = 0; kk < K1; kk += 32) {
      bf16x8 af = cvt8(arow + kk + g * 8);
#pragma unroll
      for (int nt = 0; nt < 8; ++nt) {
        bf16x8 bf = *(const bf16x8*)(BT1 + (size_t)(nt * 16 + c) * ldb1 + kk + g * 8);
        acc[nt] = __builtin_amdgcn_mfma_f32_16x16x32_bf16(af, bf, acc[nt], 0, 0, 0);
      }
    }
  } else {
    const __bf16* arow = A1b + (size_t)(rowbase + c) * lda1;
    for (int kk = 0; kk < K1; kk += 32) {
      bf16x8 af = *(const bf16x8*)(arow + kk + g * 8);
#pragma unroll
      for (int nt = 0; nt < 8; ++nt) {
        bf16x8 bf = *(const bf16x8*)(BT1 + (size_t)(nt * 16 + c) * ldb1 + kk + g * 8);
        acc[nt] = __builtin_amdgcn_mfma_f32_16x16x32_bf16(af, bf, acc[nt], 0, 0, 0);
      }
    }
  }
  if (A2b) {
    const __bf16* arow2 = A2b + (size_t)(rowbase + c) * lda2;
    for (int kk = 0; kk < K2; kk += 32) {
      bf16x8 af = *(const bf16x8*)(arow2 + kk + g * 8);
#pragma unroll
      for (int nt = 0; nt < 8; ++nt) {
        bf16x8 bf = *(const bf16x8*)(BT2 + (size_t)(nt * 16 + c) * ldb2 + kk + g * 8);
        acc[nt] = __builtin_amdgcn_mfma_f32_16x16x32_bf16(af, bf, acc[nt], 0, 0, 0);
      }
    }
  }

#pragma unroll
  for (int q = 0; q < 4; ++q) {
    int r = rowbase + g * 4 + q;
    float gmul = 0.f;
    if (gbias) gmul = cnt[r] ? 1.f : 0.f;
    const float* vrow = vtab ? (vtab + (size_t)vidx[r] * 128) : nullptr;
#pragma unroll
    for (int nt = 0; nt < 8; ++nt) {
      int n = nt * 16 + c;
      float v = acc[nt][q];
      if (cbias) v += cbias[n];
      if (gbias) v += gmul * gbias[n];
      if (vrow) v += vrow[n];
      if (do_relu) v = fmaxf(v, 0.f);
      if (Cb) Cb[(size_t)r * 128 + n] = (__bf16)v;
      else    Cf[(size_t)r * 128 + n] = v;
    }
  }
}

extern "C" void kernel_launch(void* const* d_in, const int* in_sizes, int n_in,
                              void* d_out, int out_size, void* d_ws, size_t ws_size,
                              hipStream_t stream) {
  const float* x    = (const float*)d_in[0];
  const int*   ei   = (const int*)d_in[1];
  const float* ea   = (const float*)d_in[2];
  const float* u    = (const float*)d_in[3];
  const int*   batch= (const int*)d_in[4];
  const float* W1a  = (const float*)d_in[5];
  const float* b1a  = (const float*)d_in[6];
  const float* W1b  = (const float*)d_in[7];
  const float* b1b  = (const float*)d_in[8];
  const float* W2a  = (const float*)d_in[9];
  const float* b2a  = (const float*)d_in[10];
  const float* W2b  = (const float*)d_in[11];
  const float* b2b  = (const float*)d_in[12];

  char* ws = (char*)d_ws;
  __bf16* WTya   = (__bf16*)(ws);                 // 32768
  __bf16* WTeb   = (__bf16*)(ws + 32768);         // 16384
  __bf16* WT2c   = (__bf16*)(ws + 49152);         // 32768
  __bf16* WT2bT  = (__bf16*)(ws + 81920);         // 32768
  __bf16* WT2d   = (__bf16*)(ws + 114688);        // 32768
  float*  vtab   = (float*)(ws + 147456);         // 32768
  float*  bc     = (float*)(ws + 180224);         // 512
  int*    cnt0   = (int*)(ws + 180736);           // 160,000
  int*    cnt1   = (int*)(ws + 340736);           // 160,000
  int*    offs0  = (int*)(ws + 500736);           // 160,000
  int*    offs1  = (int*)(ws + 660736);           // 160,000
  int*    cntT   = (int*)(ws + 820736);           // 160,000
  int*    sedge  = (int*)(ws + 980736);           // 2,560,000 (chunk0; chunk1 at +320k ints)
  __bf16* Yb     = (__bf16*)(ws + 3540736);       // 10,240,000 (y; meanb alias after E)
  __bf16* partb  = (__bf16*)(ws + 13780736);      // 10,240,000 (2-chunk partial sums)
  __bf16* TMP    = (__bf16*)(ws + 24020736);      // 163.84 MB (1-chunk) / 81.92 MB (2-chunk)
  __bf16* meanb  = Yb;                            // R final output (Yb dead by then)
  __bf16* h1b    = TMP;                           // h1 (TMP dead after R)

  const size_t NEED1 = 24020736ull + 163840000ull;  // 187,860,736
  int nch = (ws_size >= NEED1) ? 1 : 2;
  int ech = NE / nch;                               // 640000 or 320000

  // zero histogram counters (cnt0+cnt1 contiguous)
  hipMemsetAsync(ws + 180736, 0, 320000, stream);

  prep<<<385, 256, 0, stream>>>(W1a, W2a, W2b, W1b, b1b, u,
                                WTya, WTeb, WT2c, WT2bT, WT2d, vtab, bc);

  hist2<<<2500, 256, 0, stream>>>(ei, cnt0, cnt1, ech);
  scan2<<<nch, 1024, 0, stream>>>(cnt0, offs0, cnt1, offs1);
  scatter2<<<2500, 256, 0, stream>>>(ei, offs0, offs1, sedge, sedge + ech, ech);
  const int* cntTot = cnt0;
  if (nch == 2) {
    totk<<<157, 256, 0, stream>>>(cnt0, cnt1, cntT);
    cntTot = cntT;
  }

  // y = x @ W1a_top + b1a -> bf16
  mlp_gemm<<<625, 256, 0, stream>>>(x, nullptr, 128, 128, WTya, 128,
                                    nullptr, 0, 0, nullptr, 0,
                                    nullptr, b1a, nullptr, nullptr, nullptr,
                                    0, nullptr, Yb);

  if (nch == 1) {
    edge_E<<<NE / 64, 256, 0, stream>>>(ea, ei, WTeb, Yb, TMP, 0);
    node_R<<<NN / 4, 256, 0, stream>>>(TMP, sedge, cnt0, offs0,
                                       nullptr, cntTot, 0, 1, meanb);
  } else {
    edge_E<<<ech / 64, 256, 0, stream>>>(ea, ei, WTeb, Yb, TMP, 0);
    node_R<<<NN / 4, 256, 0, stream>>>(TMP, sedge, cnt0, offs0,
                                       nullptr, nullptr, 0, 0, partb);
    edge_E<<<ech / 64, 256, 0, stream>>>(ea, ei, WTeb, Yb, TMP, ech);
    node_R<<<NN / 4, 256, 0, stream>>>(TMP, sedge + ech, cnt1, offs1,
                                       partb, cntTot, ech, 1, meanb);
  }

  // h1 = relu(x@WT2c + mean@WT2d + b2a + [cnt>0]*bc + vtab[batch]) -> bf16
  mlp_gemm<<<625, 256, 0, stream>>>(x, nullptr, 128, 128, WT2c, 128,
                                    meanb, 128, 128, WT2d, 128,
                                    cntTot, b2a, bc, vtab, batch,
                                    1, nullptr, h1b);

  // out = h1 @ W2b + b2b -> f32
  mlp_gemm<<<625, 256, 0, stream>>>(nullptr, h1b, 128, 128, WT2bT, 128,
                                    nullptr, 0, 0, nullptr, 0,
                                    nullptr, b2b, nullptr, nullptr, nullptr,
                                    0, (float*)d_out, nullptr);
}

// Round 5
// 389.130 us; speedup vs baseline: 1.0710x; 1.0558x over previous
//
#include <hip/hip_runtime.h>
#include <hip/hip_bf16.h>

// NodeModel fused GNN block, round 5: scatter-on-write E + streaming R.
//   y     = x @ W1a[0:128] + b1a                          (bf16, 40k x 128)
//   TMP[pose[e]] = bf16(relu(y[row_e] + EA[e]@W1a[128:192]))  (E: stream reads,
//                                                          scattered row writes)
//   mean  = (contiguous segment sum of TMP per node) / max(cnt,1)  (R: streaming)
//   h1    = relu(x@W2c + mean@(W1b@W2a_mid) + b2a + [cnt>0]*bc + (u@W2a_u)[batch])
//   out   = h1 @ W2b + b2b

typedef __bf16 bf16x8 __attribute__((ext_vector_type(8)));
typedef float f32x4v __attribute__((ext_vector_type(4)));

#define NN 40000
#define NE 640000

__device__ inline bf16x8 cvt8(const float* __restrict__ p) {
  f32x4v a = *(const f32x4v*)p;
  f32x4v b = *(const f32x4v*)(p + 4);
  bf16x8 r;
  r[0] = (__bf16)a[0]; r[1] = (__bf16)a[1]; r[2] = (__bf16)a[2]; r[3] = (__bf16)a[3];
  r[4] = (__bf16)b[0]; r[5] = (__bf16)b[1]; r[6] = (__bf16)b[2]; r[7] = (__bf16)b[3];
  return r;
}

// ---------------- prep: bf16 B^T weight tables + small folds ----------------
__global__ __launch_bounds__(256) void prep(
    const float* __restrict__ W1a, const float* __restrict__ W2a,
    const float* __restrict__ W2b, const float* __restrict__ W1b,
    const float* __restrict__ b1b, const float* __restrict__ u,
    __bf16* __restrict__ WTya,   // 128x128 (W1a rows 0..127 ^T)
    __bf16* __restrict__ WTeb,   // 128x64  (W1a rows 128..191 ^T)
    __bf16* __restrict__ WT2c,   // 128x128 (W2a rows 0..127 ^T)
    __bf16* __restrict__ WT2bT,  // 128x128
    __bf16* __restrict__ WT2d,   // 128x128 ((W1b @ W2a[128:256])^T)
    float* __restrict__ vtab,    // 64x128  (u @ W2a[256:320])
    float* __restrict__ bc)      // 128     (b1b @ W2a[128:256])
{
  int b = blockIdx.x, t = threadIdx.x;
  if (b < 64) {
    int idx = b * 256 + t; int n = idx & 127; int k = idx >> 7;
    WTya[n * 128 + k] = (__bf16)W1a[k * 128 + n];
  } else if (b < 96) {
    int idx = (b - 64) * 256 + t; int n = idx & 127; int k = idx >> 7;   // k 0..63
    WTeb[n * 64 + k] = (__bf16)W1a[(128 + k) * 128 + n];
  } else if (b < 160) {
    int idx = (b - 96) * 256 + t; int n = idx & 127; int k = idx >> 7;
    WT2c[n * 128 + k] = (__bf16)W2a[k * 128 + n];
  } else if (b < 224) {
    int idx = (b - 160) * 256 + t; int n = idx & 127; int k = idx >> 7;
    WT2bT[n * 128 + k] = (__bf16)W2b[k * 128 + n];
  } else if (b < 256) {
    int idx = (b - 224) * 256 + t; int n = idx & 127; int gi = idx >> 7;
    float s = 0.f;
    for (int k = 0; k < 64; ++k) s += u[gi * 64 + k] * W2a[(256 + k) * 128 + n];
    vtab[gi * 128 + n] = s;
  } else if (b == 256) {
    if (t < 128) {
      float s = 0.f;
      for (int j = 0; j < 128; ++j) s += b1b[j] * W2a[(128 + j) * 128 + t];
      bc[t] = s;
    }
  } else {
    int k = b - 257;
    if (t < 128) {
      float s = 0.f;
      for (int j = 0; j < 128; ++j) s += W1b[k * 128 + j] * W2a[(128 + j) * 128 + t];
      WT2d[t * 128 + k] = (__bf16)s;
    }
  }
}

// ---------------- per-chunk counting sort (inverse permutation only) --------
__global__ __launch_bounds__(256) void hist2(const int* __restrict__ EI,
                                             int* __restrict__ cnt0,
                                             int* __restrict__ cnt1, int ech) {
  int e = blockIdx.x * 256 + threadIdx.x;   // grid covers NE exactly
  int col = EI[NE + e];
  if (e < ech) atomicAdd(&cnt0[col], 1);
  else         atomicAdd(&cnt1[col], 1);
}

__global__ __launch_bounds__(1024) void scan2(const int* __restrict__ cnt0,
                                              int* __restrict__ offs0,
                                              const int* __restrict__ cnt1,
                                              int* __restrict__ offs1) {
  const int* cnt = blockIdx.x ? cnt1 : cnt0;
  int* offs      = blockIdx.x ? offs1 : offs0;
  __shared__ int part[1024];
  int t = threadIdx.x;
  int base = t * 40;
  int s = 0;
  for (int k = 0; k < 40; ++k) { int idx = base + k; if (idx < NN) s += cnt[idx]; }
  part[t] = s;
  __syncthreads();
  for (int off = 1; off < 1024; off <<= 1) {
    int v = (t >= off) ? part[t - off] : 0;
    __syncthreads();
    part[t] += v;
    __syncthreads();
  }
  int pre = part[t] - s;
  for (int k = 0; k < 40; ++k) {
    int idx = base + k;
    if (idx < NN) { offs[idx] = pre; pre += cnt[idx]; }
  }
}

// pose[e] = chunk-local sorted slot of edge e
__global__ __launch_bounds__(256) void scatter2(const int* __restrict__ EI,
                                                int* __restrict__ offs0,
                                                int* __restrict__ offs1,
                                                int* __restrict__ pose, int ech) {
  int e = blockIdx.x * 256 + threadIdx.x;
  int col = EI[NE + e];
  if (e < ech) pose[e] = atomicAdd(&offs0[col], 1);
  else         pose[e] = atomicAdd(&offs1[col], 1);
}

__global__ __launch_bounds__(256) void totk(const int* __restrict__ c0,
                                            const int* __restrict__ c1,
                                            int* __restrict__ ct) {
  int i = blockIdx.x * 256 + threadIdx.x;
  if (i < NN) ct[i] = c0[i] + c1[i];
}

// ---------------- E: streaming edge GEMM + y-add + relu, scattered store ----
// block = 256 thr = 4 waves x 16 edges = 64 edges; grid = chunk_edges/64.
__global__ __launch_bounds__(256) void edge_E(
    const float* __restrict__ EA,    // 640000x64 f32
    const int* __restrict__ EI,      // [2][640000]
    const int* __restrict__ pose,    // chunk-local sorted slot per edge
    const __bf16* __restrict__ WTeb, // 128x64
    const __bf16* __restrict__ Yb,   // 40000x128 bf16
    __bf16* __restrict__ TMP,        // chunk_edges x 128 bf16, SORTED order
    int e0)                          // chunk base edge id
{
  __shared__ __bf16 vb16[64 * 136];
  __shared__ int lrow[64], lpos[64];
  int t = threadIdx.x;
  int i0l = blockIdx.x * 64;          // chunk-local base
  if (t < 64) {
    lrow[t] = EI[e0 + i0l + t];
    lpos[t] = pose[e0 + i0l + t];
  }
  __syncthreads();

  int lane = t & 63, w = t >> 6, g = lane >> 4, c = lane & 15;
  f32x4v acc[8];
#pragma unroll
  for (int nt = 0; nt < 8; ++nt) acc[nt] = (f32x4v)(0.f);

  const float* arow = EA + (size_t)(e0 + i0l + w * 16 + c) * 64;
#pragma unroll
  for (int kk = 0; kk < 64; kk += 32) {
    bf16x8 af = cvt8(arow + kk + g * 8);
#pragma unroll
    for (int nt = 0; nt < 8; ++nt) {
      bf16x8 bf = *(const bf16x8*)(WTeb + (nt * 16 + c) * 64 + kk + g * 8);
      acc[nt] = __builtin_amdgcn_mfma_f32_16x16x32_bf16(af, bf, acc[nt], 0, 0, 0);
    }
  }

  // stage the 64 needed y-rows into LDS with coalesced 16B loads
#pragma unroll
  for (int k2 = 0; k2 < 4; ++k2) {
    int flat = t + k2 * 256;              // 0..1023 = 64 rows x 16 chunks
    int row = flat >> 4, c8 = flat & 15;
    bf16x8 vv = *(const bf16x8*)(Yb + (size_t)lrow[row] * 128 + c8 * 8);
    *(bf16x8*)(vb16 + row * 136 + c8 * 8) = vv;
  }
  __syncthreads();

  // read own y fragments from LDS (own wave's 16 rows only)
  float yv[4][8];
#pragma unroll
  for (int q = 0; q < 4; ++q) {
    int r = w * 16 + g * 4 + q;
#pragma unroll
    for (int nt = 0; nt < 8; ++nt)
      yv[q][nt] = (float)vb16[r * 136 + nt * 16 + c];
  }
  // overwrite own rows with relu(acc + y) — no cross-wave hazard (own region)
#pragma unroll
  for (int q = 0; q < 4; ++q) {
    int r = w * 16 + g * 4 + q;
#pragma unroll
    for (int nt = 0; nt < 8; ++nt)
      vb16[r * 136 + nt * 16 + c] = (__bf16)fmaxf(acc[nt][q] + yv[q][nt], 0.f);
  }
  __syncthreads();

  // scattered 256B-row stores to sorted slots (writes don't stall the wave)
#pragma unroll
  for (int k2 = 0; k2 < 4; ++k2) {
    int flat = t + k2 * 256;
    int row = flat >> 4, c8 = flat & 15;
    bf16x8 vv = *(const bf16x8*)(vb16 + row * 136 + c8 * 8);
    *(bf16x8*)(TMP + (size_t)lpos[row] * 128 + c8 * 8) = vv;
  }
}

// ---------------- R: streaming segment reduce (contiguous per node) ---------
// wave per node, lane owns cols {2*lane, 2*lane+1}; block = 4 nodes.
__global__ __launch_bounds__(256) void node_R(
    const __bf16* __restrict__ TMP,    // chunk rows in sorted order
    const int* __restrict__ cntc,      // per-node in-chunk count
    const int* __restrict__ offsc,     // per-node END offset (post-scatter)
    const __bf16* __restrict__ partial,// partial sums from prev chunk (or null)
    const int* __restrict__ cntT,      // total counts (final only)
    int fin,
    __bf16* __restrict__ outb)         // partial sums or final mean
{
  int node = blockIdx.x * 4 + (threadIdx.x >> 6);  // grid*4 == NN exactly
  int lane = threadIdx.x & 63;
  int m = cntc[node];
  int start = offsc[node] - m;
  float s0 = 0.f, s1 = 0.f;
  const __bf16* base = TMP + (size_t)start * 128 + lane * 2;
#pragma unroll 4
  for (int j = 0; j < m; ++j) {
    unsigned uu = *(const unsigned*)(base + (size_t)j * 128);
    s0 += __builtin_bit_cast(float, uu << 16);
    s1 += __builtin_bit_cast(float, uu & 0xffff0000u);
  }
  if (partial) {
    unsigned pu = *(const unsigned*)(partial + (size_t)node * 128 + lane * 2);
    s0 += __builtin_bit_cast(float, pu << 16);
    s1 += __builtin_bit_cast(float, pu & 0xffff0000u);
  }
  if (fin) {
    float inv = 1.f / fmaxf((float)cntT[node], 1.f);
    s0 *= inv; s1 *= inv;
  }
  unsigned r0 = (unsigned)__builtin_bit_cast(unsigned short, (__bf16)s0);
  unsigned r1 = (unsigned)__builtin_bit_cast(unsigned short, (__bf16)s1);
  *(unsigned*)(outb + (size_t)node * 128 + lane * 2) = r0 | (r1 << 16);
}

// ---------------- node-level GEMM (N=128) ----------------------------------
__global__ __launch_bounds__(256) void mlp_gemm(
    const float* __restrict__ A1f, const __bf16* __restrict__ A1b,
    int K1, int lda1, const __bf16* __restrict__ BT1, int ldb1,
    const __bf16* __restrict__ A2b, int K2, int lda2,
    const __bf16* __restrict__ BT2, int ldb2,
    const int* __restrict__ cnt,
    const float* __restrict__ cbias, const float* __restrict__ gbias,
    const float* __restrict__ vtab, const int* __restrict__ vidx,
    int do_relu, float* __restrict__ Cf, __bf16* __restrict__ Cb) {
  int lane = threadIdx.x & 63;
  int wave = threadIdx.x >> 6;
  int rowbase = blockIdx.x * 64 + wave * 16;
  int g = lane >> 4, c = lane & 15;

  f32x4v acc[8];
#pragma unroll
  for (int nt = 0; nt < 8; ++nt) acc[nt] = (f32x4v)(0.f);

  if (A1f) {
    const float* arow = A1f + (size_t)(rowbase + c) * lda1;
    for (int kk = 0; kk < K1; kk += 32) {
      bf16x8 af = cvt8(arow + kk + g * 8);
#pragma unroll
      for (int nt = 0; nt < 8; ++nt) {
        bf16x8 bf = *(const bf16x8*)(BT1 + (size_t)(nt * 16 + c) * ldb1 + kk + g * 8);
        acc[nt] = __builtin_amdgcn_mfma_f32_16x16x32_bf16(af, bf, acc[nt], 0, 0, 0);
      }
    }
  } else {
    const __bf16* arow = A1b + (size_t)(rowbase + c) * lda1;
    for (int kk = 0; kk < K1; kk += 32) {
      bf16x8 af = *(const bf16x8*)(arow + kk + g * 8);
#pragma unroll
      for (int nt = 0; nt < 8; ++nt) {
        bf16x8 bf = *(const bf16x8*)(BT1 + (size_t)(nt * 16 + c) * ldb1 + kk + g * 8);
        acc[nt] = __builtin_amdgcn_mfma_f32_16x16x32_bf16(af, bf, acc[nt], 0, 0, 0);
      }
    }
  }
  if (A2b) {
    const __bf16* arow2 = A2b + (size_t)(rowbase + c) * lda2;
    for (int kk = 0; kk < K2; kk += 32) {
      bf16x8 af = *(const bf16x8*)(arow2 + kk + g * 8);
#pragma unroll
      for (int nt = 0; nt < 8; ++nt) {
        bf16x8 bf = *(const bf16x8*)(BT2 + (size_t)(nt * 16 + c) * ldb2 + kk + g * 8);
        acc[nt] = __builtin_amdgcn_mfma_f32_16x16x32_bf16(af, bf, acc[nt], 0, 0, 0);
      }
    }
  }

#pragma unroll
  for (int q = 0; q < 4; ++q) {
    int r = rowbase + g * 4 + q;
    float gmul = 0.f;
    if (gbias) gmul = cnt[r] ? 1.f : 0.f;
    const float* vrow = vtab ? (vtab + (size_t)vidx[r] * 128) : nullptr;
#pragma unroll
    for (int nt = 0; nt < 8; ++nt) {
      int n = nt * 16 + c;
      float v = acc[nt][q];
      if (cbias) v += cbias[n];
      if (gbias) v += gmul * gbias[n];
      if (vrow) v += vrow[n];
      if (do_relu) v = fmaxf(v, 0.f);
      if (Cb) Cb[(size_t)r * 128 + n] = (__bf16)v;
      else    Cf[(size_t)r * 128 + n] = v;
    }
  }
}

extern "C" void kernel_launch(void* const* d_in, const int* in_sizes, int n_in,
                              void* d_out, int out_size, void* d_ws, size_t ws_size,
                              hipStream_t stream) {
  const float* x    = (const float*)d_in[0];
  const int*   ei   = (const int*)d_in[1];
  const float* ea   = (const float*)d_in[2];
  const float* u    = (const float*)d_in[3];
  const int*   batch= (const int*)d_in[4];
  const float* W1a  = (const float*)d_in[5];
  const float* b1a  = (const float*)d_in[6];
  const float* W1b  = (const float*)d_in[7];
  const float* b1b  = (const float*)d_in[8];
  const float* W2a  = (const float*)d_in[9];
  const float* b2a  = (const float*)d_in[10];
  const float* W2b  = (const float*)d_in[11];
  const float* b2b  = (const float*)d_in[12];

  char* ws = (char*)d_ws;
  __bf16* WTya   = (__bf16*)(ws);                 // 32768
  __bf16* WTeb   = (__bf16*)(ws + 32768);         // 16384
  __bf16* WT2c   = (__bf16*)(ws + 49152);         // 32768
  __bf16* WT2bT  = (__bf16*)(ws + 81920);         // 32768
  __bf16* WT2d   = (__bf16*)(ws + 114688);        // 32768
  float*  vtab   = (float*)(ws + 147456);         // 32768
  float*  bc     = (float*)(ws + 180224);         // 512
  int*    cnt0   = (int*)(ws + 180736);           // 160,000
  int*    cnt1   = (int*)(ws + 340736);           // 160,000
  int*    offs0  = (int*)(ws + 500736);           // 160,000
  int*    offs1  = (int*)(ws + 660736);           // 160,000
  int*    cntT   = (int*)(ws + 820736);           // 160,000
  int*    pose   = (int*)(ws + 980736);           // 2,560,000
  __bf16* Yb     = (__bf16*)(ws + 3540736);       // 10,240,000 (y; meanb alias)
  __bf16* partb  = (__bf16*)(ws + 13780736);      // 10,240,000 (2-chunk partials)
  __bf16* TMP    = (__bf16*)(ws + 24020736);      // 163.84 MB (1ch) / 81.92 MB (2ch)
  __bf16* meanb  = Yb;                            // R output (Yb dead by then)
  __bf16* h1b    = TMP;                           // h1 (TMP dead after R)

  const size_t NEED1 = 24020736ull + 163840000ull;  // 187,860,736
  int nch = (ws_size >= NEED1) ? 1 : 2;
  int ech = NE / nch;                               // 640000 or 320000

  // zero histogram counters (cnt0+cnt1 contiguous)
  hipMemsetAsync(ws + 180736, 0, 320000, stream);

  prep<<<385, 256, 0, stream>>>(W1a, W2a, W2b, W1b, b1b, u,
                                WTya, WTeb, WT2c, WT2bT, WT2d, vtab, bc);

  hist2<<<2500, 256, 0, stream>>>(ei, cnt0, cnt1, ech);
  scan2<<<nch, 1024, 0, stream>>>(cnt0, offs0, cnt1, offs1);
  scatter2<<<2500, 256, 0, stream>>>(ei, offs0, offs1, pose, ech);
  const int* cntTot = cnt0;
  if (nch == 2) {
    totk<<<157, 256, 0, stream>>>(cnt0, cnt1, cntT);
    cntTot = cntT;
  }

  // y = x @ W1a_top + b1a -> bf16
  mlp_gemm<<<625, 256, 0, stream>>>(x, nullptr, 128, 128, WTya, 128,
                                    nullptr, 0, 0, nullptr, 0,
                                    nullptr, b1a, nullptr, nullptr, nullptr,
                                    0, nullptr, Yb);

  if (nch == 1) {
    edge_E<<<NE / 64, 256, 0, stream>>>(ea, ei, pose, WTeb, Yb, TMP, 0);
    node_R<<<NN / 4, 256, 0, stream>>>(TMP, cnt0, offs0,
                                       nullptr, cntTot, 1, meanb);
  } else {
    edge_E<<<ech / 64, 256, 0, stream>>>(ea, ei, pose, WTeb, Yb, TMP, 0);
    node_R<<<NN / 4, 256, 0, stream>>>(TMP, cnt0, offs0,
                                       nullptr, nullptr, 0, partb);
    edge_E<<<ech / 64, 256, 0, stream>>>(ea, ei, pose, WTeb, Yb, TMP, ech);
    node_R<<<NN / 4, 256, 0, stream>>>(TMP, cnt1, offs1,
                                       partb, cntTot, 1, meanb);
  }

  // h1 = relu(x@WT2c + mean@WT2d + b2a + [cnt>0]*bc + vtab[batch]) -> bf16
  mlp_gemm<<<625, 256, 0, stream>>>(x, nullptr, 128, 128, WT2c, 128,
                                    meanb, 128, 128, WT2d, 128,
                                    cntTot, b2a, bc, vtab, batch,
                                    1, nullptr, h1b);

  // out = h1 @ W2b + b2b -> f32
  mlp_gemm<<<625, 256, 0, stream>>>(nullptr, h1b, 128, 128, WT2bT, 128,
                                    nullptr, 0, 0, nullptr, 0,
                                    nullptr, b2b, nullptr, nullptr, nullptr,
                                    0, (float*)d_out, nullptr);
}